// Round 1
// baseline (92.284 us; speedup 1.0000x reference)
//
#include <hip/hip_runtime.h>
#include <hip/hip_bf16.h>
#include <math.h>

#define C 8
#define K 128
#define S 64
#define L 2048
#define NB 64
#define W (L - S + 1)   // 1985
#define TW 128
#define NTW 16
#define XCS 208         // xcop stride shorts: 104 dw = 8 banks mod 32 -> conflict-free b128
#define XFS 200         // fp32 x scratch stride (192 data + 8 zero pad)

typedef __attribute__((ext_vector_type(8))) short bf16x8;
typedef __attribute__((ext_vector_type(4))) float f32x4;

__device__ __forceinline__ unsigned short f2bf(float f) {
  unsigned int u = __float_as_uint(f);
  u += 0x7FFFu + ((u >> 16) & 1u);   // RNE
  return (unsigned short)(u >> 16);
}

// packed f32x2 -> bf16x2 (v_cvt_pk_bf16_f32 on gfx950)
__device__ __forceinline__ unsigned int pkbf(float a, float b) {
  __hip_bfloat162 h = __float22bfloat162_rn(make_float2(a, b));
  return *reinterpret_cast<unsigned int*>(&h);
}

// full-wave ONLY (lane-predicated global_load_lds explodes traffic)
__device__ __forceinline__ void gll16(const void* g, void* l) {
  __builtin_amdgcn_global_load_lds((const __attribute__((address_space(1))) void*)g,
                                   (__attribute__((address_space(3))) void*)l, 16, 0, 0);
}

// prep: z-normalize shapelets -> bf16 * (-2), B-fragment order now grouped by
// CHANNEL (16 KB contiguous per c, both 64k halves inside); init out to +inf.
// sum(z^2) == S == 64 exactly (population z-norm) -> no per-k sqs needed.
__global__ __launch_bounds__(256) void prep_kernel(const float* __restrict__ sh,
                                                   unsigned short* __restrict__ shzB,
                                                   float* __restrict__ out) {
  int tid = blockIdx.x * 256 + threadIdx.x;
  if (tid < NB * K) out[tid] = __int_as_float(0x7F800000);
  int gid = blockIdx.x * 4 + (threadIdx.x >> 6);  // c*K + k
  int lane = threadIdx.x & 63;                    // = s
  float v = sh[(size_t)gid * S + lane];
  float s1 = v, s2 = v * v;
#pragma unroll
  for (int off = 32; off > 0; off >>= 1) {
    s1 += __shfl_down(s1, off);
    s2 += __shfl_down(s2, off);
  }
  s1 = __shfl(s1, 0);
  s2 = __shfl(s2, 0);
  float mu = s1 * (1.0f / S);
  float sd = sqrtf(fmaxf(s2 * (1.0f / S) - mu * mu, 0.0f));
  float z = (v - mu) / sd;
  int c = gid >> 7, k = gid & (K - 1), s = lane;
  // layout: [c][k>>6][((k>>4)&3)*2 + (s>>5)][lane'=((s>>3)&3)*16+(k&15)][s&7]
  int idx = c * 8192 + (k >> 6) * 4096 + ((((k >> 4) & 3) * 2) + (s >> 5)) * 512 +
            ((((s >> 3) & 3) * 16 + (k & 15)) * 8) + (s & 7);
  shzB[idx] = f2bf(-2.0f * z);   // bake the -2 of d2 = (sqx + 64) - 2*cross
}

// main: block = 128w x 128k (ALL k), 256 threads = 4 waves, wave tile 64w x 64k.
// Wave = (kgrp = wave>>1 selects 64k half, wgrp = wave&1 selects 64w half).
// Per wave per channel: 8 A-frag reads SHARED across 4 k-tiles, 8 B-frag reads,
// 4 sqx reads (C-operand of the first MFMA, shared across k-tiles) -> 20 ds_b128
// for 32 MFMAs (was 56:32 for the same work). B double-buffered in LDS -> ONE
// barrier per channel. LDS 63.5 KB -> 2 blocks/CU. Arithmetic order per element
// is bit-identical to the previous kernel (same mfma b0->b1 chain, fp32 sqx
// pre-bias, same channel-sum order) -> absmax unchanged.
__global__ __launch_bounds__(256, 2) void main_kernel(const float* __restrict__ x,
                                                      const unsigned short* __restrict__ shzB,
                                                      int* __restrict__ out) {
  __shared__ __align__(16) unsigned short bbuf[2][8192];   // 32 KB: double-buffered B[c]
  __shared__ __align__(16) unsigned short xcop[C][8][XCS]; // 26 KB: 8 shifted copies
  __shared__ __align__(16) float sqx[C][TW];               // 4 KB (pre-biased +64)

  const int t = threadIdx.x;
  const int lane = t & 63;
  const int wave = t >> 6;     // 0..3
  const int wgrp = wave & 1;   // w-offset 64
  const int kgrp = wave >> 1;  // 0..1 : k-offset 64*kgrp
  const int col = lane & 15;
  const int quad = lane >> 4;
  const int n = blockIdx.y;
  const int w0 = blockIdx.x * TW;
  const float* xn = x + (size_t)n * C * L;
  const unsigned short* bsrc = shzB;

  // ---- stage fp32 x segment into bbuf-as-scratch (2 ch/wave, float4/lane) ----
  float* xf = (float*)bbuf;  // 8 ch x XFS floats = 6.4 KB <= 32 KB
#pragma unroll
  for (int cc = 0; cc < 2; ++cc) {
    const int c = wave * 2 + cc;
    const int e = lane * 4;
    float4 v; v.x = v.y = v.z = v.w = 0.0f;
    if (lane < 48) {
      int g = w0 + e;
      if (g + 3 < L) {
        v = *(const float4*)(xn + c * L + g);
      } else {  // last w-tile tail; feeds masked windows only
        v.x = (g + 0 < L) ? xn[c * L + g + 0] : 0.0f;
        v.y = (g + 1 < L) ? xn[c * L + g + 1] : 0.0f;
        v.z = (g + 2 < L) ? xn[c * L + g + 2] : 0.0f;
        v.w = (g + 3 < L) ? xn[c * L + g + 3] : 0.0f;
      }
    }
    if (lane < 50) *(float4*)&xf[c * XFS + e] = v;   // lanes 48,49 zero-pad tail
  }
  __syncthreads();

  // ---- build 8 shifted bf16 copies (2 ch/wave; r=lane>>3; 12 dwords/lane/ch) ----
#pragma unroll
  for (int cc = 0; cc < 2; ++cc) {
    const int cb = wave * 2 + cc;
    const int rb = lane >> 3;         // 0..7
    const int c8 = lane & 7;
    const float* xr = xf + cb * XFS;
#pragma unroll
    for (int j = 0; j < 12; ++j) {
      int i = (c8 + j * 8) * 2;       // 0..190 even
      *(unsigned int*)&xcop[cb][rb][i] = pkbf(xr[i + rb], xr[i + rb + 1]);
    }
  }
  // ---- sliding-window fp32 sqx (+64 bias = sum(z^2)): 2 ch/wave, 2 w/lane ----
#pragma unroll
  for (int cc = 0; cc < 2; ++cc) {
    const int c = wave * 2 + cc, wl = lane * 2;
    const float* xr = xf + c * XFS;
    float p0 = 0.f, p1 = 0.f, p2 = 0.f, p3 = 0.f;
#pragma unroll
    for (int si = 0; si < S; si += 4) {
      float v0 = xr[wl + si], v1 = xr[wl + si + 1], v2 = xr[wl + si + 2], v3 = xr[wl + si + 3];
      p0 = fmaf(v0, v0, p0); p1 = fmaf(v1, v1, p1);
      p2 = fmaf(v2, v2, p2); p3 = fmaf(v3, v3, p3);
    }
    float s0 = 64.0f + (p0 + p1) + (p2 + p3);
    sqx[c][wl] = s0;
    float a = xr[wl + S], b = xr[wl];
    sqx[c][wl + 1] = s0 + a * a - b * b;
  }
  __syncthreads();  // xf dead -> bbuf free for B

  // ---- B channel 0 -> bbuf[0]: 4 full-wave gll16 per thread (16 KB) ----
#pragma unroll
  for (int i = 0; i < 4; ++i)
    gll16(bsrc + i * 2048 + t * 8, &bbuf[0][i * 2048 + wave * 512]);

  const f32x4 z4 = {0.0f, 0.0f, 0.0f, 0.0f};
  f32x4 dsum[4][4];   // [ktile][wtile]
#pragma unroll
  for (int kt = 0; kt < 4; ++kt)
#pragma unroll
    for (int wt = 0; wt < 4; ++wt) dsum[kt][wt] = z4;

  const int r8 = col & 7;
  const int abase = wgrp * 64 + (col - r8) + quad * 8;  // multiple of 8 -> b128 aligned

  for (int c = 0; c < C; ++c) {
    __syncthreads();  // B[c] landed in bbuf[c&1] (compiler drains vmcnt here)

    if (c + 1 < C) {  // prefetch into the OTHER half; lands during compute below
#pragma unroll
      for (int i = 0; i < 4; ++i)
        gll16(bsrc + (c + 1) * 8192 + i * 2048 + t * 8,
              &bbuf[(c + 1) & 1][i * 2048 + wave * 512]);
    }

    // ---- B fragments for this wave's 64k half (8 x b128, conflict-free) ----
    const unsigned short* bb = &bbuf[c & 1][kgrp * 4096];
    bf16x8 b00 = *(const bf16x8*)(bb + 0 * 512 + lane * 8);
    bf16x8 b01 = *(const bf16x8*)(bb + 1 * 512 + lane * 8);
    bf16x8 b10 = *(const bf16x8*)(bb + 2 * 512 + lane * 8);
    bf16x8 b11 = *(const bf16x8*)(bb + 3 * 512 + lane * 8);
    bf16x8 b20 = *(const bf16x8*)(bb + 4 * 512 + lane * 8);
    bf16x8 b21 = *(const bf16x8*)(bb + 5 * 512 + lane * 8);
    bf16x8 b30 = *(const bf16x8*)(bb + 6 * 512 + lane * 8);
    bf16x8 b31 = *(const bf16x8*)(bb + 7 * 512 + lane * 8);

    const unsigned short* xc = &xcop[c][r8][0];
#pragma unroll
    for (int wt = 0; wt < 4; ++wt) {
      // acc init = sqx (broadcast read, shared across the 4 k-tiles)
      f32x4 ai = *(const f32x4*)&sqx[c][wgrp * 64 + wt * 16 + quad * 4];
      // A fragments read ONCE, feed 4 k-tiles
      bf16x8 x0 = *(const bf16x8*)(xc + abase + wt * 16);
      bf16x8 x1 = *(const bf16x8*)(xc + abase + wt * 16 + 32);
      f32x4 a0 = __builtin_amdgcn_mfma_f32_16x16x32_bf16(x0, b00, ai, 0, 0, 0);
      f32x4 a1 = __builtin_amdgcn_mfma_f32_16x16x32_bf16(x0, b10, ai, 0, 0, 0);
      f32x4 a2 = __builtin_amdgcn_mfma_f32_16x16x32_bf16(x0, b20, ai, 0, 0, 0);
      f32x4 a3 = __builtin_amdgcn_mfma_f32_16x16x32_bf16(x0, b30, ai, 0, 0, 0);
      a0 = __builtin_amdgcn_mfma_f32_16x16x32_bf16(x1, b01, a0, 0, 0, 0);
      a1 = __builtin_amdgcn_mfma_f32_16x16x32_bf16(x1, b11, a1, 0, 0, 0);
      a2 = __builtin_amdgcn_mfma_f32_16x16x32_bf16(x1, b21, a2, 0, 0, 0);
      a3 = __builtin_amdgcn_mfma_f32_16x16x32_bf16(x1, b31, a3, 0, 0, 0);
#pragma unroll
      for (int i = 0; i < 4; ++i) {
        dsum[0][wt][i] += __builtin_amdgcn_sqrtf(fmaxf(a0[i], 0.0f));
        dsum[1][wt][i] += __builtin_amdgcn_sqrtf(fmaxf(a1[i], 0.0f));
        dsum[2][wt][i] += __builtin_amdgcn_sqrtf(fmaxf(a2[i], 0.0f));
        dsum[3][wt][i] += __builtin_amdgcn_sqrtf(fmaxf(a3[i], 0.0f));
      }
    }
  }

  // min over w (regs -> quad shuffles), one atomicMin per (k-tile, lane col)
  const float INF = __int_as_float(0x7F800000);
  const int wbase = w0 + wgrp * 64;
#pragma unroll
  for (int kt = 0; kt < 4; ++kt) {
    float mv = INF;
#pragma unroll
    for (int wt = 0; wt < 4; ++wt)
#pragma unroll
      for (int i = 0; i < 4; ++i) {
        int w = wbase + wt * 16 + quad * 4 + i;
        mv = (w < W) ? fminf(mv, dsum[kt][wt][i]) : mv;
      }
    mv = fminf(mv, __shfl_xor(mv, 16));
    mv = fminf(mv, __shfl_xor(mv, 32));
    if (quad == 0)
      atomicMin(&out[n * K + kgrp * 64 + kt * 16 + col], __float_as_int(mv));
  }
}

extern "C" void kernel_launch(void* const* d_in, const int* in_sizes, int n_in,
                              void* d_out, int out_size, void* d_ws, size_t ws_size,
                              hipStream_t stream) {
  const float* x = (const float*)d_in[0];    // (64, 8, 2048) fp32
  const float* sh = (const float*)d_in[1];   // (8, 128, 64) fp32
  float* out = (float*)d_out;                // (64, 1, 128) fp32
  unsigned short* shzB = (unsigned short*)d_ws;  // 128 KB bf16 B-frag layout (scaled -2)

  prep_kernel<<<256, 256, 0, stream>>>(sh, shzB, out);
  main_kernel<<<dim3(NTW, NB), 256, 0, stream>>>(x, shzB, (int*)out);
}